// Round 13
// baseline (1019.792 us; speedup 1.0000x reference)
//
#include <hip/hip_runtime.h>
#include <hip/hip_bf16.h>
#include <cstdint>

#define DEV __device__ __forceinline__

typedef float v2f __attribute__((ext_vector_type(2)));

// Problem constants (from setup_inputs)
constexpr int Bn   = 8;
constexpr int Nn   = 4096;
constexpr int Mn   = 1024;   // N / STRIDE
constexpr int Kn   = 32;     // NSAMPLE
constexpr int CIN  = 64;
constexpr int COUT = 128;

// ---------------------------------------------------------------------------
// FPS v4 helpers (R8 config + packed-f32 update; shfl index broadcast).
// ---------------------------------------------------------------------------
DEV float wave_max_f32(float x) {
#if __has_builtin(__builtin_amdgcn_update_dpp)
#define FSTEP(CTRL, RMASK)                                                      \
  {                                                                             \
    int o = __builtin_amdgcn_update_dpp(0, __float_as_int(x), CTRL, RMASK, 0xf, \
                                        false);                                 \
    x = fmaxf(x, __int_as_float(o));                                            \
  }
  FSTEP(0x111, 0xf)  // row_shr:1
  FSTEP(0x112, 0xf)  // row_shr:2
  FSTEP(0x114, 0xf)  // row_shr:4
  FSTEP(0x118, 0xf)  // row_shr:8
  FSTEP(0x142, 0xa)  // row_bcast:15 rows 1,3
  FSTEP(0x143, 0xc)  // row_bcast:31 rows 2,3
#undef FSTEP
#else
  for (int off = 1; off < 64; off <<= 1) x = fmaxf(x, __shfl_xor(x, off, 64));
#endif
  return x;  // lane 63 holds the wave max
}

DEV unsigned long long grp8_max_u64(unsigned long long k) {
#if __has_builtin(__builtin_amdgcn_update_dpp)
#define USTEP(CTRL)                                                                    \
  {                                                                                    \
    unsigned int lo = (unsigned int)__builtin_amdgcn_update_dpp(                       \
        0, (int)(unsigned int)k, CTRL, 0xf, 0xf, false);                               \
    unsigned int hi = (unsigned int)__builtin_amdgcn_update_dpp(                       \
        0, (int)(unsigned int)(k >> 32), CTRL, 0xf, 0xf, false);                       \
    unsigned long long o = ((unsigned long long)hi << 32) | lo;                        \
    if (o > k) k = o;                                                                  \
  }
  USTEP(0x111)  // row_shr:1
  USTEP(0x112)  // row_shr:2
  USTEP(0x114)  // row_shr:4
#undef USTEP
#else
  for (int off = 1; off < 8; off <<= 1) {
    unsigned int lo = __shfl_xor((unsigned int)k, off, 64);
    unsigned int hi = __shfl_xor((unsigned int)(k >> 32), off, 64);
    unsigned long long o = ((unsigned long long)hi << 32) | lo;
    if (o > k) k = o;
  }
#endif
  return k;  // lane 7 of each row holds max of that row's lanes 0..7
}

// packed squared distance for a point-pair; IEEE RN per element, no FMA
// contraction -> bit-identical to the scalar __fsub/__fmul/__fadd_rn chain.
DEV v2f d2pair(v2f px, v2f py, v2f pz, float cx, float cy, float cz) {
#pragma clang fp contract(off)
  v2f cx2 = {cx, cx}, cy2 = {cy, cy}, cz2 = {cz, cz};
  v2f dx = px - cx2;
  v2f dy = py - cy2;
  v2f dz = pz - cz2;
  return ((dx * dx) + (dy * dy)) + (dz * dz);
}

DEV uint32_t fps_round8(const float v[8], int t, unsigned long long (*part)[8], int p) {
  float v4[4]; int j4[4];
#pragma unroll
  for (int i = 0; i < 4; ++i) {
    bool r = v[2 * i + 1] > v[2 * i];
    v4[i] = r ? v[2 * i + 1] : v[2 * i];
    j4[i] = r ? 2 * i + 1 : 2 * i;
  }
  float v2[2]; int j2[2];
#pragma unroll
  for (int i = 0; i < 2; ++i) {
    bool r = v4[2 * i + 1] > v4[2 * i];
    v2[i] = r ? v4[2 * i + 1] : v4[2 * i];
    j2[i] = r ? j4[2 * i + 1] : j4[2 * i];
  }
  bool rr = v2[1] > v2[0];
  float bv = rr ? v2[1] : v2[0];
  int bj = rr ? j2[1] : j2[0];

  float wl = wave_max_f32(bv);
  float wmax = __int_as_float(__builtin_amdgcn_readlane(__float_as_int(wl), 63));
  unsigned long long mask = __ballot(bv == wmax);
  int Ls = (int)__ffsll(mask) - 1;           // lowest lane with the max
  int bjw = __shfl(bj, Ls, 64);              // its local index (Ls uniform)
  uint32_t idx = 8u * (uint32_t)((t & ~63) + Ls) + (uint32_t)bjw;
  const int sl = p & 1;
  if ((t & 63) == 0)
    part[sl][t >> 6] = ((unsigned long long)__float_as_uint(wmax) << 12) |
                       (unsigned long long)(4095u - idx);
  __syncthreads();
  unsigned long long kk = part[sl][t & 7];
  kk = grp8_max_u64(kk);
  unsigned int lo = (unsigned int)__builtin_amdgcn_readlane((int)(unsigned int)kk, 7);
  return 4095u - (lo & 4095u);
}

// ---------------------------------------------------------------------------
// Fused kernel: blocks 0..7 = FPS; blocks 8..519 = feats transpose.
// ---------------------------------------------------------------------------
__global__ __launch_bounds__(512, 1) void k_fused(const float* __restrict__ coords,
                                                  const float* __restrict__ feats,
                                                  float* __restrict__ featsT,
                                                  uint32_t* __restrict__ sidx,
                                                  float* __restrict__ outc) {
  __shared__ __align__(16) char smraw[Nn * 16];   // sp[Nn] | tile[64][65]
  __shared__ unsigned long long part[2][8];
  __shared__ uint32_t farl[Mn];
  __shared__ float s_mean[4];
  const int t = threadIdx.x;

  if (blockIdx.x >= 8) {  // ---- transpose role ----
    float (*tile)[65] = (float(*)[65])smraw;
    int bid = blockIdx.x - 8;
    int b = bid >> 6, n0 = (bid & 63) * 64;
    int lane = t & 63, grp = t >> 6;  // 8 groups of 64
    for (int r = 0; r < 8; ++r) {
      int c = grp + r * 8;
      tile[c][lane] = feats[((size_t)b * 64 + c) * 4096 + n0 + lane];
    }
    __syncthreads();
    for (int r = 0; r < 8; ++r) {
      int n = grp + r * 8;
      featsT[((size_t)b * 4096 + n0 + n) * 64 + lane] = tile[lane][n];
    }
    return;
  }

  // ---- FPS role ----
  float4* sp = (float4*)smraw;
  const int b = blockIdx.x;
  const float* cb = coords + (size_t)b * Nn * 3;
  for (int i = t; i < Nn; i += 512)
    sp[i] = make_float4(cb[3 * i], cb[3 * i + 1], cb[3 * i + 2], 0.f);
  __syncthreads();
  if (t == 0) {  // sequential in-order fp32 mean (numpy reduce order; proven)
    float ax = 0.f, ay = 0.f, az = 0.f;
    for (int i = 0; i < Nn; ++i) {
      float4 c = sp[i];
      ax = __fadd_rn(ax, c.x); ay = __fadd_rn(ay, c.y); az = __fadd_rn(az, c.z);
    }
    s_mean[0] = __fdiv_rn(ax, 4096.f);
    s_mean[1] = __fdiv_rn(ay, 4096.f);
    s_mean[2] = __fdiv_rn(az, 4096.f);
  }
  __syncthreads();

  // 8 contiguous points per thread, packed into 4 float2 pairs.
  v2f px2[4], py2[4], pz2[4], md2[4];
#pragma unroll
  for (int i = 0; i < 4; ++i) {
    float4 c0 = sp[8 * t + 2 * i];
    float4 c1 = sp[8 * t + 2 * i + 1];
    px2[i] = (v2f){c0.x, c1.x};
    py2[i] = (v2f){c0.y, c1.y};
    pz2[i] = (v2f){c0.z, c1.z};
    md2[i] = (v2f){__builtin_inff(), __builtin_inff()};
  }

  uint32_t far;
  {
    float mx = s_mean[0], my = s_mean[1], mz = s_mean[2];
    float tv[8];
#pragma unroll
    for (int i = 0; i < 4; ++i) {
      v2f s = d2pair(px2[i], py2[i], pz2[i], mx, my, mz);
      tv[2 * i] = s.x; tv[2 * i + 1] = s.y;
    }
    far = fps_round8(tv, t, part, 0);
  }

  for (int p = 1; p < Mn; ++p) {
    if (t == 0) farl[p - 1] = far;
    float4 c = sp[far];
    float tv[8];
#pragma unroll
    for (int i = 0; i < 4; ++i) {
      v2f s = d2pair(px2[i], py2[i], pz2[i], c.x, c.y, c.z);
      v2f m;
      m.x = fminf(md2[i].x, s.x);
      m.y = fminf(md2[i].y, s.y);
      md2[i] = m;
      tv[2 * i] = m.x; tv[2 * i + 1] = m.y;
    }
    far = fps_round8(tv, t, part, p);
  }
  if (t == 0) farl[Mn - 1] = far;
  __syncthreads();

  for (int i = t; i < Mn; i += 512) {
    uint32_t f = farl[i];
    sidx[b * Mn + i] = f;
    float4 c = sp[f];
    outc[(size_t)(b * Mn + i) * 3 + 0] = c.x;
    outc[(size_t)(b * Mn + i) * 3 + 1] = c.y;
    outc[(size_t)(b * Mn + i) * 3 + 2] = c.z;
  }
}

// ---------------------------------------------------------------------------
// 32-NN per query (== reference ball_query+knn fallback) + density weights.
// ---------------------------------------------------------------------------
__global__ __launch_bounds__(256) void k_knn(const float* __restrict__ coords,
                                             const uint32_t* __restrict__ sidx,
                                             uint32_t* __restrict__ gidx,
                                             float* __restrict__ wts) {
  const int q = blockIdx.x;
  const int b = q >> 10;
  const int t = threadIdx.x;
  __shared__ unsigned long long keys[Nn + 2];
  __shared__ int s_cnt;
  __shared__ float s_q[4];
  __shared__ uint32_t s_sel[32];
  __shared__ float gx[32], gy[32], gz[32], g2[32];
  __shared__ float dmat[32 * 33];
  __shared__ float kth[32];
  __shared__ float s_raw[32];
  __shared__ float s_sum;

  if (t == 0) {
    uint32_t si = sidx[q];
    const float* c = &coords[((size_t)b * Nn + si) * 3];
    s_q[0] = c[0]; s_q[1] = c[1]; s_q[2] = c[2];
  }
  __syncthreads();
  float qx = s_q[0], qy = s_q[1], qz = s_q[2];
  float q2 = __fadd_rn(__fadd_rn(__fmul_rn(qx, qx), __fmul_rn(qy, qy)), __fmul_rn(qz, qz));
  const float* cb = coords + (size_t)b * Nn * 3;

  float thr = 0.04f;
  int cnt = 0;
  while (true) {
    if (t == 0) s_cnt = 0;
    __syncthreads();
    for (int j = 0; j < 16; ++j) {
      int i = t + 256 * j;
      float cx = cb[3 * i], cy = cb[3 * i + 1], cz = cb[3 * i + 2];
      float c2  = __fadd_rn(__fadd_rn(__fmul_rn(cx, cx), __fmul_rn(cy, cy)), __fmul_rn(cz, cz));
      float dot = __fadd_rn(__fadd_rn(__fmul_rn(qx, cx), __fmul_rn(qy, cy)), __fmul_rn(qz, cz));
      float d2  = __fsub_rn(__fadd_rn(q2, c2), __fmul_rn(2.f, dot));
      float d2c = fmaxf(d2, 1e-12f);
      bool pred = (d2c <= thr);
      unsigned long long mk = __ballot(pred);
      int base = 0;
      if ((t & 63) == 0 && mk) base = atomicAdd(&s_cnt, (int)__popcll(mk));
      base = __shfl(base, 0, 64);
      if (pred) {
        int pos = base + (int)__popcll(mk & ((1ull << (t & 63)) - 1ull));
        keys[pos] = ((unsigned long long)__float_as_uint(d2c) << 32) | (uint32_t)i;
      }
    }
    __syncthreads();
    cnt = s_cnt;
    if (cnt >= 32 || thr > 1.f) break;
    thr = (thr < 0.1f) ? 0.16f : 8.f;
    __syncthreads();
  }
  if (t == 0) { keys[cnt] = ~0ull; keys[cnt + 1] = ~0ull; }
  __syncthreads();
  int cnt2 = (cnt + 1) & ~1;
  for (int i = t; i < cnt; i += 256) {
    unsigned long long ki = keys[i];
    int r = 0;
    for (int j2 = 0; j2 < cnt2; j2 += 2) {
      unsigned long long a = keys[j2], c2 = keys[j2 + 1];
      r += (a < ki) + (c2 < ki);
    }
    if (r < 32) s_sel[r] = (uint32_t)ki;
  }
  __syncthreads();
  if (t < 32) {
    uint32_t gi = s_sel[t];
    gidx[(size_t)q * 32 + t] = gi;
    const float* c = &coords[((size_t)b * Nn + gi) * 3];
    float x = c[0], y = c[1], z = c[2];
    gx[t] = x; gy[t] = y; gz[t] = z;
    g2[t] = __fadd_rn(__fadd_rn(__fmul_rn(x, x), __fmul_rn(y, y)), __fmul_rn(z, z));
  }
  __syncthreads();
  for (int p = t; p < 1024; p += 256) {
    int i = p >> 5, jj = p & 31;
    float dot = __fadd_rn(__fadd_rn(__fmul_rn(gx[i], gx[jj]), __fmul_rn(gy[i], gy[jj])),
                          __fmul_rn(gz[i], gz[jj]));
    float d2 = __fsub_rn(__fadd_rn(g2[i], g2[jj]), __fmul_rn(2.f, dot));
    float dd = sqrtf(fmaxf(d2, 1e-12f));
    if (i == jj) dd = __builtin_inff();
    dmat[i * 33 + jj] = dd;
  }
  __syncthreads();
  for (int p = t; p < 1024; p += 256) {
    int i = p >> 5, jj = p & 31;
    float v = dmat[i * 33 + jj];
    int r = 0;
    for (int c = 0; c < 32; ++c) {
      float u = dmat[i * 33 + c];
      r += (u < v) || (u == v && c < jj);
    }
    if (r == 15) kth[i] = v;
  }
  __syncthreads();
  if (t < 32) { float x = fmaxf(kth[t], 1e-8f); s_raw[t] = x * x * x; }
  __syncthreads();
  if (t == 0) {
    float s = 0.f;
    for (int i2 = 0; i2 < 32; ++i2) s += s_raw[i2];
    s_sum = fmaxf(s, 1e-8f);
  }
  __syncthreads();
  if (t < 32) wts[(size_t)q * 32 + t] = s_raw[t] / s_sum;
}

// ---------------------------------------------------------------------------
// Conv pipeline (R9/R10 tier-A proven). Tile = 4 queries x 32 neighbors.
// ---------------------------------------------------------------------------
constexpr int XST = 132;
constexpr int WST = 68;

DEV void build_x(const float* __restrict__ coords, const float* __restrict__ featsT,
                 const uint32_t* __restrict__ sidx, const uint32_t* __restrict__ gidx,
                 const float* __restrict__ W0, int b, int m0, int t,
                 float* xs, float* w0sT, uint32_t* s_gi, float* s_qc) {
  for (int i = t; i < 64 * 67; i += 256) {
    int o = i / 67, c = i - o * 67;
    w0sT[c * WST + o] = W0[i];
  }
  if (t < 128) {
    s_gi[t] = gidx[((size_t)(b * Mn + m0)) * 32 + t];
  } else if (t < 132) {
    int mm = t - 128;
    uint32_t si = sidx[b * Mn + m0 + mm];
    const float* c = &coords[((size_t)b * Nn + si) * 3];
    s_qc[mm * 3 + 0] = c[0]; s_qc[mm * 3 + 1] = c[1]; s_qc[mm * 3 + 2] = c[2];
  }
  __syncthreads();
  if (t < 128) {
    int mm = t >> 5;
    const float* c = &coords[((size_t)b * Nn + s_gi[t]) * 3];
    xs[0 * XST + t] = (c[0] - s_qc[mm * 3 + 0]) / 0.2f;
    xs[1 * XST + t] = (c[1] - s_qc[mm * 3 + 1]) / 0.2f;
    xs[2 * XST + t] = (c[2] - s_qc[mm * 3 + 2]) / 0.2f;
  }
  {
    int c = t & 63, k0g = t >> 6;
    for (int r2 = 0; r2 < 32; ++r2) {
      int kk = k0g + 4 * r2;
      xs[(size_t)(3 + c) * XST + kk] = featsT[((size_t)b * Nn + s_gi[kk]) * 64 + c];
    }
  }
  __syncthreads();
}

DEV void conv1_acc(const float* xs, const float* w0sT, int o0, int k0, float acc[32]) {
#pragma unroll
  for (int i = 0; i < 32; ++i) acc[i] = 0.f;
  for (int c = 0; c < 67; ++c) {
    float4 w  = *(const float4*)&w0sT[c * WST + o0];
    float4 xa = *(const float4*)&xs[c * XST + k0];
    float4 xb = *(const float4*)&xs[c * XST + k0 + 4];
    float wv[4] = {w.x, w.y, w.z, w.w};
    float xv[8] = {xa.x, xa.y, xa.z, xa.w, xb.x, xb.y, xb.z, xb.w};
#pragma unroll
    for (int i = 0; i < 4; ++i)
#pragma unroll
      for (int j = 0; j < 8; ++j)
        acc[i * 8 + j] = fmaf(wv[i], xv[j], acc[i * 8 + j]);
  }
}

DEV void conv2_acc(const float* hs, const float* w1sT, int o0, int k0, float acc2[32]) {
#pragma unroll
  for (int i = 0; i < 32; ++i) acc2[i] = 0.f;
  for (int c = 0; c < 64; ++c) {
    float4 w  = *(const float4*)&w1sT[c * WST + o0];
    float4 xa = *(const float4*)&hs[c * XST + k0];
    float4 xb = *(const float4*)&hs[c * XST + k0 + 4];
    float wv[4] = {w.x, w.y, w.z, w.w};
    float xv[8] = {xa.x, xa.y, xa.z, xa.w, xb.x, xb.y, xb.z, xb.w};
#pragma unroll
    for (int i = 0; i < 4; ++i)
#pragma unroll
      for (int j = 0; j < 8; ++j)
        acc2[i * 8 + j] = fmaf(wv[i], xv[j], acc2[i * 8 + j]);
  }
}

DEV unsigned short f2bf(float x) {
  __hip_bfloat16 h = __float2bfloat16(x);
  return *reinterpret_cast<unsigned short*>(&h);
}

// stats layout (floats): [0,64) s0 | [64,128) q0 | [128,256) s1 | [256,384) q1
// | [384,512) ss | [512,640) qs
__global__ __launch_bounds__(256) void k_conv1s(const float* __restrict__ coords,
                                                const float* __restrict__ featsT,
                                                const uint32_t* __restrict__ sidx,
                                                const uint32_t* __restrict__ gidx,
                                                const float* __restrict__ W0,
                                                const float* __restrict__ Ws,
                                                float* __restrict__ ys,
                                                float* __restrict__ stats,
                                                unsigned short* __restrict__ accb) {
  __shared__ float smU[13400];
  __shared__ uint32_t s_gi[128];
  __shared__ float s_qc[12];
  __shared__ float ssum[128], ssq[128];
  int t = threadIdx.x;

  if (blockIdx.x >= 2048) {  // ---- skip role ----
    float* fin  = smU;
    float* wssT = smU + 64 * 65;
    uint32_t* s_si = s_gi;
    int blk = blockIdx.x - 2048;
    int b = blk >> 4, m0 = (blk & 15) * 64;
    if (t < 64) s_si[t] = sidx[b * Mn + m0 + t];
    if (t < 128) { ssum[t] = 0.f; ssq[t] = 0.f; }
    __syncthreads();
    for (int i = t; i < 64 * 64; i += 256) {
      int mm = i >> 6, c = i & 63;
      fin[mm * 65 + c] = featsT[((size_t)b * Nn + s_si[mm]) * 64 + c];
    }
    for (int i = t; i < 128 * 64; i += 256) {
      int oo = i >> 6, cc = i & 63;
      wssT[cc * 129 + oo] = Ws[(size_t)oo * 64 + cc];
    }
    __syncthreads();
    int o = t & 127, mh = t >> 7;
    float s = 0.f, sq = 0.f;
    for (int mm = mh * 32; mm < mh * 32 + 32; ++mm) {
      float acc = 0.f;
      for (int c = 0; c < 64; ++c) acc = fmaf(wssT[c * 129 + o], fin[mm * 65 + c], acc);
      ys[((size_t)(b * Mn + m0 + mm)) * 128 + o] = acc;
      s += acc; sq = fmaf(acc, acc, sq);
    }
    atomicAdd(&ssum[o], s); atomicAdd(&ssq[o], sq);
    __syncthreads();
    if (t < 128) { atomicAdd(&stats[384 + t], ssum[t]); atomicAdd(&stats[512 + t], ssq[t]); }
    return;
  }

  float* xs = smU; float* w0sT = smU + 67 * XST;
  int blk = blockIdx.x;
  int b = blk >> 8, m0 = (blk & 255) << 2;
  if (t < 64) { ssum[t] = 0.f; ssq[t] = 0.f; }
  build_x(coords, featsT, sidx, gidx, W0, b, m0, t, xs, w0sT, s_gi, s_qc);
  int o0 = (t & 15) * 4, k0 = (t >> 4) * 8;
  float acc[32];
  conv1_acc(xs, w0sT, o0, k0, acc);
  {
    unsigned short* at = accb + (size_t)blk * 8192;
#pragma unroll
    for (int i = 0; i < 4; ++i) {
      unsigned int w[4];
#pragma unroll
      for (int q = 0; q < 4; ++q)
        w[q] = (unsigned int)f2bf(acc[i * 8 + 2 * q]) |
               ((unsigned int)f2bf(acc[i * 8 + 2 * q + 1]) << 16);
      *(uint4*)&at[(o0 + i) * 128 + k0] = make_uint4(w[0], w[1], w[2], w[3]);
    }
  }
#pragma unroll
  for (int i = 0; i < 4; ++i) {
    float s = 0.f, sq = 0.f;
#pragma unroll
    for (int j = 0; j < 8; ++j) { s += acc[i * 8 + j]; sq = fmaf(acc[i * 8 + j], acc[i * 8 + j], sq); }
    atomicAdd(&ssum[o0 + i], s); atomicAdd(&ssq[o0 + i], sq);
  }
  __syncthreads();
  if (t < 64) { atomicAdd(&stats[t], ssum[t]); atomicAdd(&stats[64 + t], ssq[t]); }
}

__global__ __launch_bounds__(256) void k_conv2c(const unsigned short* __restrict__ accb,
                                                const float* __restrict__ W1,
                                                float* __restrict__ stats,
                                                const float* __restrict__ g0,
                                                const float* __restrict__ b0,
                                                unsigned short* __restrict__ acc2b) {
  __shared__ float hs[64 * XST];
  __shared__ float w1sT[64 * WST];
  __shared__ float s_a0[64], s_c0[64];
  __shared__ float ssum[128], ssq[128];
  int blk = blockIdx.x, t = threadIdx.x;
  if (t < 128) { ssum[t] = 0.f; ssq[t] = 0.f; }
  if (t < 64) {
    float mu  = stats[t] * (1.f / 262144.f);
    float var = stats[64 + t] * (1.f / 262144.f) - mu * mu;
    float a = g0[t] / sqrtf(var + 1e-5f);
    s_a0[t] = a; s_c0[t] = b0[t] - mu * a;
  }
  const unsigned short* at = accb + (size_t)blk * 8192;
  int o = t >> 2, kb = (t & 3) * 32;
  __syncthreads();
  float a0 = s_a0[o], c0 = s_c0[o];
#pragma unroll
  for (int g = 0; g < 4; ++g) {
    uint4 v = *(const uint4*)&at[o * 128 + kb + 8 * g];
    unsigned int vv[4] = {v.x, v.y, v.z, v.w};
#pragma unroll
    for (int q = 0; q < 4; ++q) {
      float f0 = __uint_as_float((vv[q] & 0xffffu) << 16);
      float f1 = __uint_as_float(vv[q] & 0xffff0000u);
      hs[o * XST + kb + 8 * g + 2 * q]     = fmaxf(fmaf(a0, f0, c0), 0.f);
      hs[o * XST + kb + 8 * g + 2 * q + 1] = fmaxf(fmaf(a0, f1, c0), 0.f);
    }
  }
  int o0 = (t & 15) * 4, k0 = (t >> 4) * 8;
  unsigned short* at2 = acc2b + (size_t)blk * 16384;
  for (int p = 0; p < 2; ++p) {
    __syncthreads();
    for (int i = t; i < 64 * 64; i += 256) {
      int oo = i >> 6, cc = i & 63;
      w1sT[cc * WST + oo] = W1[(size_t)(64 * p + oo) * 64 + cc];
    }
    __syncthreads();
    float acc2[32];
    conv2_acc(hs, w1sT, o0, k0, acc2);
    {
#pragma unroll
      for (int j = 0; j < 8; ++j) {
        unsigned int lo = (unsigned int)f2bf(acc2[0 * 8 + j]) |
                          ((unsigned int)f2bf(acc2[1 * 8 + j]) << 16);
        unsigned int hi = (unsigned int)f2bf(acc2[2 * 8 + j]) |
                          ((unsigned int)f2bf(acc2[3 * 8 + j]) << 16);
        *(uint2*)&at2[(size_t)(k0 + j) * 128 + 64 * p + o0] = make_uint2(lo, hi);
      }
    }
#pragma unroll
    for (int i = 0; i < 4; ++i) {
      float s = 0.f, sq = 0.f;
#pragma unroll
      for (int j = 0; j < 8; ++j) { s += acc2[i * 8 + j]; sq = fmaf(acc2[i * 8 + j], acc2[i * 8 + j], sq); }
      atomicAdd(&ssum[64 * p + o0 + i], s); atomicAdd(&ssq[64 * p + o0 + i], sq);
    }
  }
  __syncthreads();
  if (t < 128) { atomicAdd(&stats[128 + t], ssum[t]); atomicAdd(&stats[256 + t], ssq[t]); }
}

__global__ __launch_bounds__(256) void k_outc2(const unsigned short* __restrict__ acc2b,
                                               const float* __restrict__ wts,
                                               const float* __restrict__ ys,
                                               const float* __restrict__ stats,
                                               const float* __restrict__ g1,
                                               const float* __restrict__ b1,
                                               const float* __restrict__ gs,
                                               const float* __restrict__ bs,
                                               float* __restrict__ out_feat) {
  __shared__ float s_a1[128], s_c1[128], s_as[128], s_cs[128];
  __shared__ float sw[4 * 36];
  __shared__ float red[128 * 5];
  int blk = blockIdx.x, t = threadIdx.x;
  int b = blk >> 8, m0 = (blk & 255) << 2;
  if (t < 128) {
    float mu  = stats[128 + t] * (1.f / 262144.f);
    float var = stats[256 + t] * (1.f / 262144.f) - mu * mu;
    float a = g1[t] / sqrtf(var + 1e-5f);
    s_a1[t] = a; s_c1[t] = b1[t] - mu * a;
    float mus  = stats[384 + t] * (1.f / 8192.f);
    float vars = stats[512 + t] * (1.f / 8192.f) - mus * mus;
    float as = gs[t] / sqrtf(vars + 1e-5f);
    s_as[t] = as; s_cs[t] = bs[t] - mus * as;
    sw[(t >> 5) * 36 + (t & 31)] = wts[((size_t)(b * Mn + m0)) * 32 + t];
  }
  __syncthreads();
  int o2 = t & 127, mh = t >> 7;
  float a1 = s_a1[o2], c1 = s_c1[o2], as = s_as[o2], cs = s_cs[o2];
  const unsigned short* base = acc2b + (size_t)blk * 16384;
#pragma unroll
  for (int mi = 0; mi < 2; ++mi) {
    int m = mh * 2 + mi;
    const unsigned short* col = base + (size_t)(m * 32) * 128 + o2;
    const float* swr = &sw[m * 36];
    float r = 0.f;
#pragma unroll
    for (int k = 0; k < 32; ++k) {
      float f = __uint_as_float((unsigned int)col[(size_t)k * 128] << 16);
      float msg = fmaxf(fmaf(a1, f, c1), 0.f);
      r = fmaf(msg, swr[k], r);
    }
    float ysv = ys[((size_t)(b * Mn + m0 + m)) * 128 + o2];
    red[o2 * 5 + m] = fmaxf(r + fmaf(as, ysv, cs), 0.f);
  }
  __syncthreads();
  for (int e = t; e < 512; e += 256) {
    int oo = e >> 2, mm = e & 3;
    out_feat[(size_t)b * 131072 + (size_t)oo * 1024 + m0 + mm] = red[oo * 5 + mm];
  }
}

// ---------------------------------------------------------------------------
extern "C" void kernel_launch(void* const* d_in, const int* in_sizes, int n_in,
                              void* d_out, int out_size, void* d_ws, size_t ws_size,
                              hipStream_t stream) {
  const float* coords = (const float*)d_in[0];
  const float* feats  = (const float*)d_in[1];
  const float* W0 = (const float*)d_in[2];
  const float* g0 = (const float*)d_in[3];
  const float* b0 = (const float*)d_in[4];
  const float* W1 = (const float*)d_in[5];
  const float* g1 = (const float*)d_in[6];
  const float* b1 = (const float*)d_in[7];
  const float* Ws = (const float*)d_in[8];
  const float* gs = (const float*)d_in[9];
  const float* bs = (const float*)d_in[10];

  float* out_coords = (float*)d_out;
  float* out_feat   = out_coords + (size_t)Bn * Mn * 3;

  char* w = (char*)d_ws;
  float*    featsT = (float*)w;    w += (size_t)Bn * Nn * CIN * 4;   // 8 MB
  uint32_t* sidx   = (uint32_t*)w; w += (size_t)Bn * Mn * 4;
  uint32_t* gidx   = (uint32_t*)w; w += (size_t)Bn * Mn * Kn * 4;
  float*    wts    = (float*)w;    w += (size_t)Bn * Mn * Kn * 4;
  float*    ys     = (float*)w;    w += (size_t)Bn * Mn * COUT * 4;  // 4 MB
  unsigned short* accb = (unsigned short*)w; w += (size_t)2048 * 8192 * 2;  // 33.5 MB
  float*    stats  = (float*)w;    w += 1280 * 4;
  unsigned short* acc2b = (unsigned short*)w; w += (size_t)2048 * 16384 * 2; // 67 MB

  hipMemsetAsync(stats, 0, 640 * 4, stream);
  hipLaunchKernelGGL(k_fused,  dim3(520),  dim3(512), 0, stream,
                     coords, feats, featsT, sidx, out_coords);
  hipLaunchKernelGGL(k_knn,    dim3(8192), dim3(256), 0, stream,
                     coords, sidx, gidx, wts);
  hipLaunchKernelGGL(k_conv1s, dim3(2176), dim3(256), 0, stream,
                     coords, featsT, sidx, gidx, W0, Ws, ys, stats, accb);
  hipLaunchKernelGGL(k_conv2c, dim3(2048), dim3(256), 0, stream,
                     accb, W1, stats, g0, b0, acc2b);
  hipLaunchKernelGGL(k_outc2,  dim3(2048), dim3(256), 0, stream,
                     acc2b, wts, ys, stats, g1, b1, gs, bs, out_feat);
}

// Round 14
// 1011.081 us; speedup vs baseline: 1.0086x; 1.0086x over previous
//
#include <hip/hip_runtime.h>
#include <hip/hip_bf16.h>
#include <cstdint>

#define DEV __device__ __forceinline__

// Problem constants (from setup_inputs)
constexpr int Bn   = 8;
constexpr int Nn   = 4096;
constexpr int Mn   = 1024;   // N / STRIDE
constexpr int Kn   = 32;     // NSAMPLE
constexpr int CIN  = 64;
constexpr int COUT = 128;

// ---------------------------------------------------------------------------
// FPS v4 helpers (R8/R12 config: best measured 694 us; shfl index broadcast).
// ---------------------------------------------------------------------------
DEV float wave_max_f32(float x) {
#if __has_builtin(__builtin_amdgcn_update_dpp)
#define FSTEP(CTRL, RMASK)                                                      \
  {                                                                             \
    int o = __builtin_amdgcn_update_dpp(0, __float_as_int(x), CTRL, RMASK, 0xf, \
                                        false);                                 \
    x = fmaxf(x, __int_as_float(o));                                            \
  }
  FSTEP(0x111, 0xf)  // row_shr:1
  FSTEP(0x112, 0xf)  // row_shr:2
  FSTEP(0x114, 0xf)  // row_shr:4
  FSTEP(0x118, 0xf)  // row_shr:8
  FSTEP(0x142, 0xa)  // row_bcast:15 rows 1,3
  FSTEP(0x143, 0xc)  // row_bcast:31 rows 2,3
#undef FSTEP
#else
  for (int off = 1; off < 64; off <<= 1) x = fmaxf(x, __shfl_xor(x, off, 64));
#endif
  return x;  // lane 63 holds the wave max
}

DEV unsigned long long grp8_max_u64(unsigned long long k) {
#if __has_builtin(__builtin_amdgcn_update_dpp)
#define USTEP(CTRL)                                                                    \
  {                                                                                    \
    unsigned int lo = (unsigned int)__builtin_amdgcn_update_dpp(                       \
        0, (int)(unsigned int)k, CTRL, 0xf, 0xf, false);                               \
    unsigned int hi = (unsigned int)__builtin_amdgcn_update_dpp(                       \
        0, (int)(unsigned int)(k >> 32), CTRL, 0xf, 0xf, false);                       \
    unsigned long long o = ((unsigned long long)hi << 32) | lo;                        \
    if (o > k) k = o;                                                                  \
  }
  USTEP(0x111)  // row_shr:1
  USTEP(0x112)  // row_shr:2
  USTEP(0x114)  // row_shr:4
#undef USTEP
#else
  for (int off = 1; off < 8; off <<= 1) {
    unsigned int lo = __shfl_xor((unsigned int)k, off, 64);
    unsigned int hi = __shfl_xor((unsigned int)(k >> 32), off, 64);
    unsigned long long o = ((unsigned long long)hi << 32) | lo;
    if (o > k) k = o;
  }
#endif
  return k;  // lane 7 of each row holds max of that row's lanes 0..7
}

DEV uint32_t fps_round8(const float v[8], int t, unsigned long long (*part)[8], int p) {
  float v4[4]; int j4[4];
#pragma unroll
  for (int i = 0; i < 4; ++i) {
    bool r = v[2 * i + 1] > v[2 * i];
    v4[i] = r ? v[2 * i + 1] : v[2 * i];
    j4[i] = r ? 2 * i + 1 : 2 * i;
  }
  float v2[2]; int j2[2];
#pragma unroll
  for (int i = 0; i < 2; ++i) {
    bool r = v4[2 * i + 1] > v4[2 * i];
    v2[i] = r ? v4[2 * i + 1] : v4[2 * i];
    j2[i] = r ? j4[2 * i + 1] : j4[2 * i];
  }
  bool rr = v2[1] > v2[0];
  float bv = rr ? v2[1] : v2[0];
  int bj = rr ? j2[1] : j2[0];

  float wl = wave_max_f32(bv);
  float wmax = __int_as_float(__builtin_amdgcn_readlane(__float_as_int(wl), 63));
  unsigned long long mask = __ballot(bv == wmax);
  int Ls = (int)__ffsll(mask) - 1;           // lowest lane with the max
  int bjw = __shfl(bj, Ls, 64);              // its local index (Ls uniform)
  uint32_t idx = 8u * (uint32_t)((t & ~63) + Ls) + (uint32_t)bjw;
  const int sl = p & 1;
  if ((t & 63) == 0)
    part[sl][t >> 6] = ((unsigned long long)__float_as_uint(wmax) << 12) |
                       (unsigned long long)(4095u - idx);
  __syncthreads();
  unsigned long long kk = part[sl][t & 7];
  kk = grp8_max_u64(kk);
  unsigned int lo = (unsigned int)__builtin_amdgcn_readlane((int)(unsigned int)kk, 7);
  return 4095u - (lo & 4095u);
}

// ---------------------------------------------------------------------------
// Fused kernel: blocks 0..7 = FPS; blocks 8..519 = feats transpose.
// (Best measured split configuration: 694 us.)
// ---------------------------------------------------------------------------
__global__ __launch_bounds__(512, 1) void k_fused(const float* __restrict__ coords,
                                                  const float* __restrict__ feats,
                                                  float* __restrict__ featsT,
                                                  uint32_t* __restrict__ sidx,
                                                  float* __restrict__ outc) {
  __shared__ __align__(16) char smraw[Nn * 16];   // sp[Nn] | tile[64][65]
  __shared__ unsigned long long part[2][8];
  __shared__ uint32_t farl[Mn];
  __shared__ float s_mean[4];
  const int t = threadIdx.x;

  if (blockIdx.x >= 8) {  // ---- transpose role ----
    float (*tile)[65] = (float(*)[65])smraw;
    int bid = blockIdx.x - 8;
    int b = bid >> 6, n0 = (bid & 63) * 64;
    int lane = t & 63, grp = t >> 6;  // 8 groups of 64
    for (int r = 0; r < 8; ++r) {
      int c = grp + r * 8;
      tile[c][lane] = feats[((size_t)b * 64 + c) * 4096 + n0 + lane];
    }
    __syncthreads();
    for (int r = 0; r < 8; ++r) {
      int n = grp + r * 8;
      featsT[((size_t)b * 4096 + n0 + n) * 64 + lane] = tile[lane][n];
    }
    return;
  }

  // ---- FPS role ----
  float4* sp = (float4*)smraw;
  const int b = blockIdx.x;
  const float* cb = coords + (size_t)b * Nn * 3;
  for (int i = t; i < Nn; i += 512)
    sp[i] = make_float4(cb[3 * i], cb[3 * i + 1], cb[3 * i + 2], 0.f);
  __syncthreads();
  if (t == 0) {  // sequential in-order fp32 mean (numpy reduce order; proven)
    float ax = 0.f, ay = 0.f, az = 0.f;
    for (int i = 0; i < Nn; ++i) {
      float4 c = sp[i];
      ax = __fadd_rn(ax, c.x); ay = __fadd_rn(ay, c.y); az = __fadd_rn(az, c.z);
    }
    s_mean[0] = __fdiv_rn(ax, 4096.f);
    s_mean[1] = __fdiv_rn(ay, 4096.f);
    s_mean[2] = __fdiv_rn(az, 4096.f);
  }
  __syncthreads();

  float px[8], py[8], pz[8], md[8];
#pragma unroll
  for (int j = 0; j < 8; ++j) {
    float4 c = sp[8 * t + j];                   // contiguous per thread
    px[j] = c.x; py[j] = c.y; pz[j] = c.z;
    md[j] = __builtin_inff();
  }

  uint32_t far;
  {
    float mx = s_mean[0], my = s_mean[1], mz = s_mean[2];
    float tv[8];
#pragma unroll
    for (int j = 0; j < 8; ++j) {
      float dx = __fsub_rn(px[j], mx), dy = __fsub_rn(py[j], my), dz = __fsub_rn(pz[j], mz);
      tv[j] = __fadd_rn(__fadd_rn(__fmul_rn(dx, dx), __fmul_rn(dy, dy)), __fmul_rn(dz, dz));
    }
    far = fps_round8(tv, t, part, 0);
  }

  for (int p = 1; p < Mn; ++p) {
    if (t == 0) farl[p - 1] = far;
    float4 c = sp[far];
#pragma unroll
    for (int j = 0; j < 8; ++j) {
      float dx = __fsub_rn(px[j], c.x), dy = __fsub_rn(py[j], c.y), dz = __fsub_rn(pz[j], c.z);
      float d = __fadd_rn(__fadd_rn(__fmul_rn(dx, dx), __fmul_rn(dy, dy)), __fmul_rn(dz, dz));
      md[j] = fminf(md[j], d);
    }
    far = fps_round8(md, t, part, p);
  }
  if (t == 0) farl[Mn - 1] = far;
  __syncthreads();

  for (int i = t; i < Mn; i += 512) {
    uint32_t f = farl[i];
    sidx[b * Mn + i] = f;
    float4 c = sp[f];
    outc[(size_t)(b * Mn + i) * 3 + 0] = c.x;
    outc[(size_t)(b * Mn + i) * 3 + 1] = c.y;
    outc[(size_t)(b * Mn + i) * 3 + 2] = c.z;
  }
}

// ---------------------------------------------------------------------------
// 32-NN per query (== reference ball_query+knn fallback) + density weights.
// ---------------------------------------------------------------------------
__global__ __launch_bounds__(256) void k_knn(const float* __restrict__ coords,
                                             const uint32_t* __restrict__ sidx,
                                             uint32_t* __restrict__ gidx,
                                             float* __restrict__ wts) {
  const int q = blockIdx.x;
  const int b = q >> 10;
  const int t = threadIdx.x;
  __shared__ unsigned long long keys[Nn + 2];
  __shared__ int s_cnt;
  __shared__ float s_q[4];
  __shared__ uint32_t s_sel[32];
  __shared__ float gx[32], gy[32], gz[32], g2[32];
  __shared__ float dmat[32 * 33];
  __shared__ float kth[32];
  __shared__ float s_raw[32];
  __shared__ float s_sum;

  if (t == 0) {
    uint32_t si = sidx[q];
    const float* c = &coords[((size_t)b * Nn + si) * 3];
    s_q[0] = c[0]; s_q[1] = c[1]; s_q[2] = c[2];
  }
  __syncthreads();
  float qx = s_q[0], qy = s_q[1], qz = s_q[2];
  float q2 = __fadd_rn(__fadd_rn(__fmul_rn(qx, qx), __fmul_rn(qy, qy)), __fmul_rn(qz, qz));
  const float* cb = coords + (size_t)b * Nn * 3;

  float thr = 0.04f;
  int cnt = 0;
  while (true) {
    if (t == 0) s_cnt = 0;
    __syncthreads();
    for (int j = 0; j < 16; ++j) {
      int i = t + 256 * j;
      float cx = cb[3 * i], cy = cb[3 * i + 1], cz = cb[3 * i + 2];
      float c2  = __fadd_rn(__fadd_rn(__fmul_rn(cx, cx), __fmul_rn(cy, cy)), __fmul_rn(cz, cz));
      float dot = __fadd_rn(__fadd_rn(__fmul_rn(qx, cx), __fmul_rn(qy, cy)), __fmul_rn(qz, cz));
      float d2  = __fsub_rn(__fadd_rn(q2, c2), __fmul_rn(2.f, dot));
      float d2c = fmaxf(d2, 1e-12f);
      bool pred = (d2c <= thr);
      unsigned long long mk = __ballot(pred);
      int base = 0;
      if ((t & 63) == 0 && mk) base = atomicAdd(&s_cnt, (int)__popcll(mk));
      base = __shfl(base, 0, 64);
      if (pred) {
        int pos = base + (int)__popcll(mk & ((1ull << (t & 63)) - 1ull));
        keys[pos] = ((unsigned long long)__float_as_uint(d2c) << 32) | (uint32_t)i;
      }
    }
    __syncthreads();
    cnt = s_cnt;
    if (cnt >= 32 || thr > 1.f) break;
    thr = (thr < 0.1f) ? 0.16f : 8.f;
    __syncthreads();
  }
  if (t == 0) { keys[cnt] = ~0ull; keys[cnt + 1] = ~0ull; }
  __syncthreads();
  int cnt2 = (cnt + 1) & ~1;
  for (int i = t; i < cnt; i += 256) {
    unsigned long long ki = keys[i];
    int r = 0;
    for (int j2 = 0; j2 < cnt2; j2 += 2) {
      unsigned long long a = keys[j2], c2 = keys[j2 + 1];
      r += (a < ki) + (c2 < ki);
    }
    if (r < 32) s_sel[r] = (uint32_t)ki;
  }
  __syncthreads();
  if (t < 32) {
    uint32_t gi = s_sel[t];
    gidx[(size_t)q * 32 + t] = gi;
    const float* c = &coords[((size_t)b * Nn + gi) * 3];
    float x = c[0], y = c[1], z = c[2];
    gx[t] = x; gy[t] = y; gz[t] = z;
    g2[t] = __fadd_rn(__fadd_rn(__fmul_rn(x, x), __fmul_rn(y, y)), __fmul_rn(z, z));
  }
  __syncthreads();
  for (int p = t; p < 1024; p += 256) {
    int i = p >> 5, jj = p & 31;
    float dot = __fadd_rn(__fadd_rn(__fmul_rn(gx[i], gx[jj]), __fmul_rn(gy[i], gy[jj])),
                          __fmul_rn(gz[i], gz[jj]));
    float d2 = __fsub_rn(__fadd_rn(g2[i], g2[jj]), __fmul_rn(2.f, dot));
    float dd = sqrtf(fmaxf(d2, 1e-12f));
    if (i == jj) dd = __builtin_inff();
    dmat[i * 33 + jj] = dd;
  }
  __syncthreads();
  for (int p = t; p < 1024; p += 256) {
    int i = p >> 5, jj = p & 31;
    float v = dmat[i * 33 + jj];
    int r = 0;
    for (int c = 0; c < 32; ++c) {
      float u = dmat[i * 33 + c];
      r += (u < v) || (u == v && c < jj);
    }
    if (r == 15) kth[i] = v;
  }
  __syncthreads();
  if (t < 32) { float x = fmaxf(kth[t], 1e-8f); s_raw[t] = x * x * x; }
  __syncthreads();
  if (t == 0) {
    float s = 0.f;
    for (int i2 = 0; i2 < 32; ++i2) s += s_raw[i2];
    s_sum = fmaxf(s, 1e-8f);
  }
  __syncthreads();
  if (t < 32) wts[(size_t)q * 32 + t] = s_raw[t] / s_sum;
}

// ---------------------------------------------------------------------------
// Conv pipeline (R9/R10/R12 tier-A proven). Tile = 4 queries x 32 neighbors.
// ---------------------------------------------------------------------------
constexpr int XST = 132;
constexpr int WST = 68;

DEV void build_x(const float* __restrict__ coords, const float* __restrict__ featsT,
                 const uint32_t* __restrict__ sidx, const uint32_t* __restrict__ gidx,
                 const float* __restrict__ W0, int b, int m0, int t,
                 float* xs, float* w0sT, uint32_t* s_gi, float* s_qc) {
  for (int i = t; i < 64 * 67; i += 256) {
    int o = i / 67, c = i - o * 67;
    w0sT[c * WST + o] = W0[i];
  }
  if (t < 128) {
    s_gi[t] = gidx[((size_t)(b * Mn + m0)) * 32 + t];
  } else if (t < 132) {
    int mm = t - 128;
    uint32_t si = sidx[b * Mn + m0 + mm];
    const float* c = &coords[((size_t)b * Nn + si) * 3];
    s_qc[mm * 3 + 0] = c[0]; s_qc[mm * 3 + 1] = c[1]; s_qc[mm * 3 + 2] = c[2];
  }
  __syncthreads();
  if (t < 128) {
    int mm = t >> 5;
    const float* c = &coords[((size_t)b * Nn + s_gi[t]) * 3];
    xs[0 * XST + t] = (c[0] - s_qc[mm * 3 + 0]) / 0.2f;
    xs[1 * XST + t] = (c[1] - s_qc[mm * 3 + 1]) / 0.2f;
    xs[2 * XST + t] = (c[2] - s_qc[mm * 3 + 2]) / 0.2f;
  }
  {
    int c = t & 63, k0g = t >> 6;
    for (int r2 = 0; r2 < 32; ++r2) {
      int kk = k0g + 4 * r2;
      xs[(size_t)(3 + c) * XST + kk] = featsT[((size_t)b * Nn + s_gi[kk]) * 64 + c];
    }
  }
  __syncthreads();
}

DEV void conv1_acc(const float* xs, const float* w0sT, int o0, int k0, float acc[32]) {
#pragma unroll
  for (int i = 0; i < 32; ++i) acc[i] = 0.f;
  for (int c = 0; c < 67; ++c) {
    float4 w  = *(const float4*)&w0sT[c * WST + o0];
    float4 xa = *(const float4*)&xs[c * XST + k0];
    float4 xb = *(const float4*)&xs[c * XST + k0 + 4];
    float wv[4] = {w.x, w.y, w.z, w.w};
    float xv[8] = {xa.x, xa.y, xa.z, xa.w, xb.x, xb.y, xb.z, xb.w};
#pragma unroll
    for (int i = 0; i < 4; ++i)
#pragma unroll
      for (int j = 0; j < 8; ++j)
        acc[i * 8 + j] = fmaf(wv[i], xv[j], acc[i * 8 + j]);
  }
}

DEV void conv2_acc(const float* hs, const float* w1sT, int o0, int k0, float acc2[32]) {
#pragma unroll
  for (int i = 0; i < 32; ++i) acc2[i] = 0.f;
  for (int c = 0; c < 64; ++c) {
    float4 w  = *(const float4*)&w1sT[c * WST + o0];
    float4 xa = *(const float4*)&hs[c * XST + k0];
    float4 xb = *(const float4*)&hs[c * XST + k0 + 4];
    float wv[4] = {w.x, w.y, w.z, w.w};
    float xv[8] = {xa.x, xa.y, xa.z, xa.w, xb.x, xb.y, xb.z, xb.w};
#pragma unroll
    for (int i = 0; i < 4; ++i)
#pragma unroll
      for (int j = 0; j < 8; ++j)
        acc2[i * 8 + j] = fmaf(wv[i], xv[j], acc2[i * 8 + j]);
  }
}

DEV unsigned short f2bf(float x) {
  __hip_bfloat16 h = __float2bfloat16(x);
  return *reinterpret_cast<unsigned short*>(&h);
}

// stats layout (floats): [0,64) s0 | [64,128) q0 | [128,256) s1 | [256,384) q1
// | [384,512) ss | [512,640) qs
__global__ __launch_bounds__(256) void k_conv1s(const float* __restrict__ coords,
                                                const float* __restrict__ featsT,
                                                const uint32_t* __restrict__ sidx,
                                                const uint32_t* __restrict__ gidx,
                                                const float* __restrict__ W0,
                                                const float* __restrict__ Ws,
                                                float* __restrict__ ys,
                                                float* __restrict__ stats,
                                                unsigned short* __restrict__ accb) {
  __shared__ float smU[13400];
  __shared__ uint32_t s_gi[128];
  __shared__ float s_qc[12];
  __shared__ float ssum[128], ssq[128];
  int t = threadIdx.x;

  if (blockIdx.x >= 2048) {  // ---- skip role ----
    float* fin  = smU;
    float* wssT = smU + 64 * 65;
    uint32_t* s_si = s_gi;
    int blk = blockIdx.x - 2048;
    int b = blk >> 4, m0 = (blk & 15) * 64;
    if (t < 64) s_si[t] = sidx[b * Mn + m0 + t];
    if (t < 128) { ssum[t] = 0.f; ssq[t] = 0.f; }
    __syncthreads();
    for (int i = t; i < 64 * 64; i += 256) {
      int mm = i >> 6, c = i & 63;
      fin[mm * 65 + c] = featsT[((size_t)b * Nn + s_si[mm]) * 64 + c];
    }
    for (int i = t; i < 128 * 64; i += 256) {
      int oo = i >> 6, cc = i & 63;
      wssT[cc * 129 + oo] = Ws[(size_t)oo * 64 + cc];
    }
    __syncthreads();
    int o = t & 127, mh = t >> 7;
    float s = 0.f, sq = 0.f;
    for (int mm = mh * 32; mm < mh * 32 + 32; ++mm) {
      float acc = 0.f;
      for (int c = 0; c < 64; ++c) acc = fmaf(wssT[c * 129 + o], fin[mm * 65 + c], acc);
      ys[((size_t)(b * Mn + m0 + mm)) * 128 + o] = acc;
      s += acc; sq = fmaf(acc, acc, sq);
    }
    atomicAdd(&ssum[o], s); atomicAdd(&ssq[o], sq);
    __syncthreads();
    if (t < 128) { atomicAdd(&stats[384 + t], ssum[t]); atomicAdd(&stats[512 + t], ssq[t]); }
    return;
  }

  float* xs = smU; float* w0sT = smU + 67 * XST;
  int blk = blockIdx.x;
  int b = blk >> 8, m0 = (blk & 255) << 2;
  if (t < 64) { ssum[t] = 0.f; ssq[t] = 0.f; }
  build_x(coords, featsT, sidx, gidx, W0, b, m0, t, xs, w0sT, s_gi, s_qc);
  int o0 = (t & 15) * 4, k0 = (t >> 4) * 8;
  float acc[32];
  conv1_acc(xs, w0sT, o0, k0, acc);
  {
    unsigned short* at = accb + (size_t)blk * 8192;
#pragma unroll
    for (int i = 0; i < 4; ++i) {
      unsigned int w[4];
#pragma unroll
      for (int q = 0; q < 4; ++q)
        w[q] = (unsigned int)f2bf(acc[i * 8 + 2 * q]) |
               ((unsigned int)f2bf(acc[i * 8 + 2 * q + 1]) << 16);
      *(uint4*)&at[(o0 + i) * 128 + k0] = make_uint4(w[0], w[1], w[2], w[3]);
    }
  }
#pragma unroll
  for (int i = 0; i < 4; ++i) {
    float s = 0.f, sq = 0.f;
#pragma unroll
    for (int j = 0; j < 8; ++j) { s += acc[i * 8 + j]; sq = fmaf(acc[i * 8 + j], acc[i * 8 + j], sq); }
    atomicAdd(&ssum[o0 + i], s); atomicAdd(&ssq[o0 + i], sq);
  }
  __syncthreads();
  if (t < 64) { atomicAdd(&stats[t], ssum[t]); atomicAdd(&stats[64 + t], ssq[t]); }
}

__global__ __launch_bounds__(256) void k_conv2c(const unsigned short* __restrict__ accb,
                                                const float* __restrict__ W1,
                                                float* __restrict__ stats,
                                                const float* __restrict__ g0,
                                                const float* __restrict__ b0,
                                                unsigned short* __restrict__ acc2b) {
  __shared__ float hs[64 * XST];
  __shared__ float w1sT[64 * WST];
  __shared__ float s_a0[64], s_c0[64];
  __shared__ float ssum[128], ssq[128];
  int blk = blockIdx.x, t = threadIdx.x;
  if (t < 128) { ssum[t] = 0.f; ssq[t] = 0.f; }
  if (t < 64) {
    float mu  = stats[t] * (1.f / 262144.f);
    float var = stats[64 + t] * (1.f / 262144.f) - mu * mu;
    float a = g0[t] / sqrtf(var + 1e-5f);
    s_a0[t] = a; s_c0[t] = b0[t] - mu * a;
  }
  const unsigned short* at = accb + (size_t)blk * 8192;
  int o = t >> 2, kb = (t & 3) * 32;
  __syncthreads();
  float a0 = s_a0[o], c0 = s_c0[o];
#pragma unroll
  for (int g = 0; g < 4; ++g) {
    uint4 v = *(const uint4*)&at[o * 128 + kb + 8 * g];
    unsigned int vv[4] = {v.x, v.y, v.z, v.w};
#pragma unroll
    for (int q = 0; q < 4; ++q) {
      float f0 = __uint_as_float((vv[q] & 0xffffu) << 16);
      float f1 = __uint_as_float(vv[q] & 0xffff0000u);
      hs[o * XST + kb + 8 * g + 2 * q]     = fmaxf(fmaf(a0, f0, c0), 0.f);
      hs[o * XST + kb + 8 * g + 2 * q + 1] = fmaxf(fmaf(a0, f1, c0), 0.f);
    }
  }
  int o0 = (t & 15) * 4, k0 = (t >> 4) * 8;
  unsigned short* at2 = acc2b + (size_t)blk * 16384;
  for (int p = 0; p < 2; ++p) {
    __syncthreads();
    for (int i = t; i < 64 * 64; i += 256) {
      int oo = i >> 6, cc = i & 63;
      w1sT[cc * WST + oo] = W1[(size_t)(64 * p + oo) * 64 + cc];
    }
    __syncthreads();
    float acc2[32];
    conv2_acc(hs, w1sT, o0, k0, acc2);
    {
#pragma unroll
      for (int j = 0; j < 8; ++j) {
        unsigned int lo = (unsigned int)f2bf(acc2[0 * 8 + j]) |
                          ((unsigned int)f2bf(acc2[1 * 8 + j]) << 16);
        unsigned int hi = (unsigned int)f2bf(acc2[2 * 8 + j]) |
                          ((unsigned int)f2bf(acc2[3 * 8 + j]) << 16);
        *(uint2*)&at2[(size_t)(k0 + j) * 128 + 64 * p + o0] = make_uint2(lo, hi);
      }
    }
#pragma unroll
    for (int i = 0; i < 4; ++i) {
      float s = 0.f, sq = 0.f;
#pragma unroll
      for (int j = 0; j < 8; ++j) { s += acc2[i * 8 + j]; sq = fmaf(acc2[i * 8 + j], acc2[i * 8 + j], sq); }
      atomicAdd(&ssum[64 * p + o0 + i], s); atomicAdd(&ssq[64 * p + o0 + i], sq);
    }
  }
  __syncthreads();
  if (t < 128) { atomicAdd(&stats[128 + t], ssum[t]); atomicAdd(&stats[256 + t], ssq[t]); }
}

__global__ __launch_bounds__(256) void k_outc2(const unsigned short* __restrict__ acc2b,
                                               const float* __restrict__ wts,
                                               const float* __restrict__ ys,
                                               const float* __restrict__ stats,
                                               const float* __restrict__ g1,
                                               const float* __restrict__ b1,
                                               const float* __restrict__ gs,
                                               const float* __restrict__ bs,
                                               float* __restrict__ out_feat) {
  __shared__ float s_a1[128], s_c1[128], s_as[128], s_cs[128];
  __shared__ float sw[4 * 36];
  __shared__ float red[128 * 5];
  int blk = blockIdx.x, t = threadIdx.x;
  int b = blk >> 8, m0 = (blk & 255) << 2;
  if (t < 128) {
    float mu  = stats[128 + t] * (1.f / 262144.f);
    float var = stats[256 + t] * (1.f / 262144.f) - mu * mu;
    float a = g1[t] / sqrtf(var + 1e-5f);
    s_a1[t] = a; s_c1[t] = b1[t] - mu * a;
    float mus  = stats[384 + t] * (1.f / 8192.f);
    float vars = stats[512 + t] * (1.f / 8192.f) - mus * mus;
    float as = gs[t] / sqrtf(vars + 1e-5f);
    s_as[t] = as; s_cs[t] = bs[t] - mus * as;
    sw[(t >> 5) * 36 + (t & 31)] = wts[((size_t)(b * Mn + m0)) * 32 + t];
  }
  __syncthreads();
  int o2 = t & 127, mh = t >> 7;
  float a1 = s_a1[o2], c1 = s_c1[o2], as = s_as[o2], cs = s_cs[o2];
  const unsigned short* base = acc2b + (size_t)blk * 16384;
#pragma unroll
  for (int mi = 0; mi < 2; ++mi) {
    int m = mh * 2 + mi;
    const unsigned short* col = base + (size_t)(m * 32) * 128 + o2;
    const float* swr = &sw[m * 36];
    float r = 0.f;
#pragma unroll
    for (int k = 0; k < 32; ++k) {
      float f = __uint_as_float((unsigned int)col[(size_t)k * 128] << 16);
      float msg = fmaxf(fmaf(a1, f, c1), 0.f);
      r = fmaf(msg, swr[k], r);
    }
    float ysv = ys[((size_t)(b * Mn + m0 + m)) * 128 + o2];
    red[o2 * 5 + m] = fmaxf(r + fmaf(as, ysv, cs), 0.f);
  }
  __syncthreads();
  for (int e = t; e < 512; e += 256) {
    int oo = e >> 2, mm = e & 3;
    out_feat[(size_t)b * 131072 + (size_t)oo * 1024 + m0 + mm] = red[oo * 5 + mm];
  }
}

// ---------------------------------------------------------------------------
extern "C" void kernel_launch(void* const* d_in, const int* in_sizes, int n_in,
                              void* d_out, int out_size, void* d_ws, size_t ws_size,
                              hipStream_t stream) {
  const float* coords = (const float*)d_in[0];
  const float* feats  = (const float*)d_in[1];
  const float* W0 = (const float*)d_in[2];
  const float* g0 = (const float*)d_in[3];
  const float* b0 = (const float*)d_in[4];
  const float* W1 = (const float*)d_in[5];
  const float* g1 = (const float*)d_in[6];
  const float* b1 = (const float*)d_in[7];
  const float* Ws = (const float*)d_in[8];
  const float* gs = (const float*)d_in[9];
  const float* bs = (const float*)d_in[10];

  float* out_coords = (float*)d_out;
  float* out_feat   = out_coords + (size_t)Bn * Mn * 3;

  char* w = (char*)d_ws;
  float*    featsT = (float*)w;    w += (size_t)Bn * Nn * CIN * 4;   // 8 MB
  uint32_t* sidx   = (uint32_t*)w; w += (size_t)Bn * Mn * 4;
  uint32_t* gidx   = (uint32_t*)w; w += (size_t)Bn * Mn * Kn * 4;
  float*    wts    = (float*)w;    w += (size_t)Bn * Mn * Kn * 4;
  float*    ys     = (float*)w;    w += (size_t)Bn * Mn * COUT * 4;  // 4 MB
  unsigned short* accb = (unsigned short*)w; w += (size_t)2048 * 8192 * 2;  // 33.5 MB
  float*    stats  = (float*)w;    w += 1280 * 4;
  unsigned short* acc2b = (unsigned short*)w; w += (size_t)2048 * 16384 * 2; // 67 MB

  hipMemsetAsync(stats, 0, 640 * 4, stream);
  hipLaunchKernelGGL(k_fused,  dim3(520),  dim3(512), 0, stream,
                     coords, feats, featsT, sidx, out_coords);
  hipLaunchKernelGGL(k_knn,    dim3(8192), dim3(256), 0, stream,
                     coords, sidx, gidx, wts);
  hipLaunchKernelGGL(k_conv1s, dim3(2176), dim3(256), 0, stream,
                     coords, featsT, sidx, gidx, W0, Ws, ys, stats, accb);
  hipLaunchKernelGGL(k_conv2c, dim3(2048), dim3(256), 0, stream,
                     accb, W1, stats, g0, b0, acc2b);
  hipLaunchKernelGGL(k_outc2,  dim3(2048), dim3(256), 0, stream,
                     acc2b, wts, ys, stats, g1, b1, gs, bs, out_feat);
}